// Round 3
// 691.511 us; speedup vs baseline: 1.0652x; 1.0652x over previous
//
#include <hip/hip_runtime.h>
#include <hip/hip_bf16.h>

// MoE (Gemma 8-expert top-2) sparse bf16 MFMA implementation.
// R4 (2nd resubmit after infra timeouts): both GEMMs on the 8-phase 256-row
// template (T2+T3+T4+T5):
//   - BM=256 row tiles (routing pads experts to 256), BK=64, 512 thr / 8 waves
//   - double-buffered 128KB LDS, one half-tile (128x64) staged per phase via
//     global_load_lds x2, counted s_waitcnt vmcnt(4) once per K-tile (never 0
//     in steady state)
//   - XOR chunk swizzle (c8 ^= row&7) applied on pre-swizzled global source
//     AND ds_read address (both-sides rule)
//   - raw s_barrier pairs per phase, s_setprio(1) around each 16-MFMA cluster
// gateup: gate/up are the two B-panels of one tile (fused gelu*up epilogue).
// down:   B-panels = two 128-col halves of a 256-col tile; atomic scatter-add.

typedef __attribute__((ext_vector_type(8))) short bf16x8;
typedef __attribute__((ext_vector_type(4))) float f32x4;

#define AS1 __attribute__((address_space(1)))
#define AS3 __attribute__((address_space(3)))

static constexpr int T_TOK = 8192;
static constexpr int HID   = 2048;
static constexpr int INTER = 1024;
static constexpr int NEXP  = 8;
static constexpr int NPAIR = T_TOK * 2;            // 16384 (token, slot) pairs
static constexpr int TM    = 256;                  // row tile (pairs), 8-phase BM
static constexpr int MAX_ROWS = NPAIR + NEXP * TM; // 18432 padded rows max
static constexpr int MAX_RT   = MAX_ROWS / TM;     // 72 row tiles max
static constexpr int OUTN = T_TOK * HID;           // 16,777,216 out elements

__device__ __forceinline__ unsigned short f2bf(float f) {
  unsigned u = __float_as_uint(f);
  u += 0x7fffu + ((u >> 16) & 1u);   // RNE
  return (unsigned short)(u >> 16);
}
__device__ __forceinline__ float bf2f(unsigned short h) {
  return __uint_as_float(((unsigned)h) << 16);
}
__device__ __forceinline__ void glds16(const void* g, void* l) {
  __builtin_amdgcn_global_load_lds((const AS1 void*)g, (AS3 void*)l, 16, 0, 0);
}

// ----------------------------------------------------------- dtype detect ---
__global__ void detect_k(const unsigned* __restrict__ xw, int* __restrict__ flagp) {
  int tid = threadIdx.x;   // 64 threads
  int cnt = 0;
  for (int i = tid; i < 256; i += 64) {
    unsigned e = (xw[i] >> 7) & 0xffu;   // exponent of low-half bf16
    cnt += (e >= 0x70u && e <= 0x8fu) ? 1 : 0;
  }
  for (int off = 32; off; off >>= 1) cnt += __shfl_down(cnt, off);
  if (tid == 0) *flagp = (cnt >= 192) ? 1 : 0;
}

// -------------------------------------------------------------- zero out ----
__global__ void zero_out_k(unsigned* __restrict__ out, const int* __restrict__ flagp) {
  int n = (*flagp) ? (OUTN / 2) : OUTN;   // u32 words
  int i = blockIdx.x * 256 + threadIdx.x;
  int stride = gridDim.x * 256;
  for (; i < n; i += stride) out[i] = 0u;
}

// ---------------------------------------------------------------- routing ---
__global__ void routing_k(const int* __restrict__ sel, const void* __restrict__ rwv,
                          int* __restrict__ rows, float* __restrict__ wgt,
                          int* __restrict__ offs, const int* __restrict__ flagp) {
  __shared__ int cnt[NEXP], cur[NEXP], offs_s[NEXP + 1];
  int flag = *flagp;
  const unsigned short* rw16 = (const unsigned short*)rwv;
  const float* rwf = (const float*)rwv;
  int tid = threadIdx.x;
  if (tid < NEXP) cnt[tid] = 0;
  __syncthreads();
  for (int p = tid; p < NPAIR; p += 256) atomicAdd(&cnt[sel[p]], 1);
  __syncthreads();
  if (tid == 0) {
    int off = 0;
    for (int e = 0; e < NEXP; ++e) {
      offs_s[e] = off; cur[e] = off;
      off += (cnt[e] + TM - 1) / TM * TM;   // pad each expert to TM rows
    }
    offs_s[NEXP] = off;
  }
  __syncthreads();
  if (tid <= NEXP) offs[tid] = offs_s[tid];
  for (int p = tid; p < NPAIR; p += 256) {
    int e = sel[p];
    int pos = atomicAdd(&cur[e], 1);
    rows[pos] = p >> 1;                                 // token index
    wgt[pos] = flag ? bf2f(rw16[p]) : rwf[p];           // routing weight
  }
  for (int e = 0; e < NEXP; ++e)
    for (int r = offs_s[e] + cnt[e] + tid; r < offs_s[e + 1]; r += 256) {
      rows[r] = 0; wgt[r] = 0.f;   // padding rows: token 0, weight 0
    }
}

// --------------------------------------------------------- x canonicalize ---
__global__ void convert_x_k(const void* __restrict__ xin,
                            unsigned short* __restrict__ xc,
                            const int* __restrict__ flagp) {
  int flag = *flagp;
  const int nvec = (T_TOK * HID) / 8;   // 8 elements per iter
  int v = blockIdx.x * 256 + threadIdx.x;
  int stride = gridDim.x * 256;
  for (; v < nvec; v += stride) {
    if (flag) {
      ((uint4*)xc)[v] = ((const uint4*)xin)[v];
    } else {
      const float4* s = (const float4*)xin;
      float4 a = s[2 * v], b = s[2 * v + 1];
      uint4 o;
      o.x = (unsigned)f2bf(a.x) | ((unsigned)f2bf(a.y) << 16);
      o.y = (unsigned)f2bf(a.z) | ((unsigned)f2bf(a.w) << 16);
      o.z = (unsigned)f2bf(b.x) | ((unsigned)f2bf(b.y) << 16);
      o.w = (unsigned)f2bf(b.z) | ((unsigned)f2bf(b.w) << 16);
      ((uint4*)xc)[v] = o;
    }
  }
}

// -------------------------------------------------------------- transpose ---
// in: [E][R][C] (fp32 or bf16) -> out: [E][C][R] bf16, 64x64 tiles.
__global__ void transpose_k(const void* __restrict__ in,
                            unsigned short* __restrict__ out, int R, int C,
                            const int* __restrict__ flagp) {
  __shared__ unsigned short tile[64][65];
  int flag = *flagp;
  int e = blockIdx.z;
  int c0 = blockIdx.x * 64, r0 = blockIdx.y * 64;
  int tid = threadIdx.x;
  if (flag) {
    const unsigned short* src = (const unsigned short*)in + (size_t)e * R * C;
    int tx = tid & 7, ty = tid >> 3;   // 8 col-groups x 32 rows
#pragma unroll
    for (int i = 0; i < 2; ++i) {
      int rr = ty + i * 32;
      uint4 v = *(const uint4*)(src + (size_t)(r0 + rr) * C + c0 + tx * 8);
      unsigned short* t = &tile[rr][tx * 8];
      t[0] = (unsigned short)v.x; t[1] = (unsigned short)(v.x >> 16);
      t[2] = (unsigned short)v.y; t[3] = (unsigned short)(v.y >> 16);
      t[4] = (unsigned short)v.z; t[5] = (unsigned short)(v.z >> 16);
      t[6] = (unsigned short)v.w; t[7] = (unsigned short)(v.w >> 16);
    }
  } else {
    const float* src = (const float*)in + (size_t)e * R * C;
    int tx = tid & 15, ty = tid >> 4;  // 16 col-groups x 16 rows
#pragma unroll
    for (int i = 0; i < 4; ++i) {
      int rr = ty + i * 16;
      float4 v = *(const float4*)(src + (size_t)(r0 + rr) * C + c0 + tx * 4);
      unsigned short* t = &tile[rr][tx * 4];
      t[0] = f2bf(v.x); t[1] = f2bf(v.y); t[2] = f2bf(v.z); t[3] = f2bf(v.w);
    }
  }
  __syncthreads();
  unsigned short* dst = out + (size_t)e * R * C;
  int tx = tid & 7, ty = tid >> 3;
#pragma unroll
  for (int i = 0; i < 2; ++i) {
    int cc = ty + i * 32;
    unsigned short a0 = tile[tx * 8 + 0][cc], a1 = tile[tx * 8 + 1][cc];
    unsigned short a2 = tile[tx * 8 + 2][cc], a3 = tile[tx * 8 + 3][cc];
    unsigned short a4 = tile[tx * 8 + 4][cc], a5 = tile[tx * 8 + 5][cc];
    unsigned short a6 = tile[tx * 8 + 6][cc], a7 = tile[tx * 8 + 7][cc];
    uint4 v;
    v.x = a0 | ((unsigned)a1 << 16); v.y = a2 | ((unsigned)a3 << 16);
    v.z = a4 | ((unsigned)a5 << 16); v.w = a6 | ((unsigned)a7 << 16);
    *(uint4*)(dst + (size_t)(c0 + cc) * R + r0 + tx * 8) = v;
  }
}

// ===================== 8-phase 256-row GEMM template ========================
// LDS slots (each 8192 shorts = 128 rows x 64 cols bf16, chunk-XOR swizzled):
//   A: slot 0=A[buf0][h0] 1=A[buf0][h1] 2=A[buf1][h0] 3=A[buf1][h1]
//   B: slot 4=B[buf0][p0] 5=B[buf0][p1] 6=B[buf1][p0] 7=B[buf1][p1]
// Per K-tile phases: ph1 A0*B0 (stage A1(next)->buf^1), ph2 A0*B1 (stage
// B0(next)), ph3 A1*B1 (stage A0(next2)->buf), ph4 A1*B0 (stage B1(next2),
// vmcnt(4), barrier). WAR-safe: each region's last ds_read completes >=2
// barriers before its overwriting stage issues; vmcnt(4)+barrier at tile end
// guarantees all of tile u+1's halves landed while tile u+2's 2 newest stages
// stay in flight (counted, never drained to 0 in steady state).

__device__ __forceinline__ const bf16x8* ldf(const unsigned short* sm, int slot,
                                             int r, int c8) {
  return (const bf16x8*)(sm + slot * 8192 + r * 64 + ((c8 ^ (r & 7)) << 3));
}
__device__ __forceinline__ void stage_half(const unsigned short* p0,
                                           const unsigned short* p1,
                                           unsigned short* dst) {
  glds16(p0, dst);
  glds16(p1, dst + 4096);
}

#define MFMA8(AH, BH, B)                                                       \
  _Pragma("unroll") for (int i_ = 0; i_ < 4; ++i_) {                           \
    _Pragma("unroll") for (int j_ = 0; j_ < 2; ++j_) {                         \
      acc[AH][BH][i_][j_] = __builtin_amdgcn_mfma_f32_16x16x32_bf16(           \
          a[i_][0], B[j_][0], acc[AH][BH][i_][j_], 0, 0, 0);                   \
      acc[AH][BH][i_][j_] = __builtin_amdgcn_mfma_f32_16x16x32_bf16(           \
          a[i_][1], B[j_][1], acc[AH][BH][i_][j_], 0, 0, 0);                   \
    }                                                                          \
  }

template <int BUF, bool S1, bool S2, int VM>
__device__ __forceinline__ void ktile(
    unsigned short* sm, int wbase, int rA, int rB, int lquad,
    const unsigned short* pA00, const unsigned short* pA01,
    const unsigned short* pA10, const unsigned short* pA11,
    const unsigned short* pB00, const unsigned short* pB01,
    const unsigned short* pB10, const unsigned short* pB11,
    int ko1, int ko2, f32x4 (&acc)[2][2][4][2]) {
  bf16x8 a[4][2], b0[2][2], b1[2][2];
  // -------- phase 1: A0 x B0 ; stage A1(u+1) -> buf^1
#pragma unroll
  for (int i = 0; i < 4; ++i)
#pragma unroll
    for (int k = 0; k < 2; ++k)
      a[i][k] = *ldf(sm, BUF * 2 + 0, rA + i * 16, k * 4 + lquad);
#pragma unroll
  for (int j = 0; j < 2; ++j)
#pragma unroll
    for (int k = 0; k < 2; ++k)
      b0[j][k] = *ldf(sm, 4 + BUF * 2 + 0, rB + j * 16, k * 4 + lquad);
  if constexpr (S1)
    stage_half(pA10 + ko1, pA11 + ko1, sm + ((BUF ^ 1) * 2 + 1) * 8192 + wbase);
  __builtin_amdgcn_s_barrier();
  asm volatile("s_waitcnt lgkmcnt(0)" ::: "memory");
  __builtin_amdgcn_s_setprio(1);
  MFMA8(0, 0, b0);
  __builtin_amdgcn_s_setprio(0);
  __builtin_amdgcn_s_barrier();
  // -------- phase 2: A0 x B1 ; stage B0(u+1) -> buf^1
#pragma unroll
  for (int j = 0; j < 2; ++j)
#pragma unroll
    for (int k = 0; k < 2; ++k)
      b1[j][k] = *ldf(sm, 4 + BUF * 2 + 1, rB + j * 16, k * 4 + lquad);
  if constexpr (S1)
    stage_half(pB00 + ko1, pB01 + ko1, sm + (4 + (BUF ^ 1) * 2 + 0) * 8192 + wbase);
  __builtin_amdgcn_s_barrier();
  asm volatile("s_waitcnt lgkmcnt(0)" ::: "memory");
  __builtin_amdgcn_s_setprio(1);
  MFMA8(0, 1, b1);
  __builtin_amdgcn_s_setprio(0);
  __builtin_amdgcn_s_barrier();
  // -------- phase 3: A1 x B1 ; stage A0(u+2) -> buf
#pragma unroll
  for (int i = 0; i < 4; ++i)
#pragma unroll
    for (int k = 0; k < 2; ++k)
      a[i][k] = *ldf(sm, BUF * 2 + 1, rA + i * 16, k * 4 + lquad);
  if constexpr (S2)
    stage_half(pA00 + ko2, pA01 + ko2, sm + (BUF * 2 + 0) * 8192 + wbase);
  __builtin_amdgcn_s_barrier();
  asm volatile("s_waitcnt lgkmcnt(0)" ::: "memory");
  __builtin_amdgcn_s_setprio(1);
  MFMA8(1, 1, b1);
  __builtin_amdgcn_s_setprio(0);
  __builtin_amdgcn_s_barrier();
  // -------- phase 4: A1 x B0 ; stage B1(u+2) -> buf ; counted vmcnt
  if constexpr (S2)
    stage_half(pB10 + ko2, pB11 + ko2, sm + (4 + BUF * 2 + 1) * 8192 + wbase);
  __builtin_amdgcn_s_barrier();
  __builtin_amdgcn_s_setprio(1);
  MFMA8(1, 0, b0);
  __builtin_amdgcn_s_setprio(0);
  if constexpr (VM == 4)
    asm volatile("s_waitcnt vmcnt(4)" ::: "memory");
  else if constexpr (VM == 0)
    asm volatile("s_waitcnt vmcnt(0)" ::: "memory");
  __builtin_amdgcn_s_barrier();
}

// ------------------------------------------------------ gate/up fused GEMM ---
// act[r][i] = gelu_tanh(xc[rows[r]] . gwT[e][i]) * (xc[rows[r]] . uwT[e][i])
__global__ __launch_bounds__(512, 2) void gemm_gateup8(
    const unsigned short* __restrict__ xc,    // [T][HID] bf16
    const unsigned short* __restrict__ gwT,   // [E][INTER][HID] bf16
    const unsigned short* __restrict__ uwT,   // [E][INTER][HID] bf16
    const int* __restrict__ rows, const int* __restrict__ offs,
    unsigned short* __restrict__ act) {
  extern __shared__ unsigned short sm[];
  int nRT = offs[NEXP] >> 8;
  int rowTile = blockIdx.x >> 3;
  if (rowTile >= nRT) return;
  int nt = blockIdx.x & 7;                    // 8 n-tiles of 128 act cols
  int row0 = rowTile << 8;
  int e = 0;
  while (row0 >= offs[e + 1]) ++e;

  int tid = threadIdx.x;
  int lane = tid & 63, lrow = lane & 15, lquad = lane >> 4;
  int wave = tid >> 6;
  int wmg = wave >> 2, wng = wave & 3;
  int wbase = wave << 9;                      // *512 shorts
  int rA = wmg * 64 + lrow;
  int rB = wng * 32 + lrow;

  int sr = tid >> 3;                          // 0..63 row in staging round
  int swz = ((tid & 7) ^ (sr & 7)) << 3;      // pre-swizzled source chunk

  const unsigned short* pA00 = xc + (size_t)rows[row0 + sr] * HID + swz;
  const unsigned short* pA01 = xc + (size_t)rows[row0 + 64 + sr] * HID + swz;
  const unsigned short* pA10 = xc + (size_t)rows[row0 + 128 + sr] * HID + swz;
  const unsigned short* pA11 = xc + (size_t)rows[row0 + 192 + sr] * HID + swz;
  const unsigned short* gB = gwT + ((size_t)e * INTER + (size_t)nt * 128) * HID;
  const unsigned short* uB = uwT + ((size_t)e * INTER + (size_t)nt * 128) * HID;
  const unsigned short* pB00 = gB + (size_t)sr * HID + swz;
  const unsigned short* pB01 = gB + (size_t)(64 + sr) * HID + swz;
  const unsigned short* pB10 = uB + (size_t)sr * HID + swz;
  const unsigned short* pB11 = uB + (size_t)(64 + sr) * HID + swz;

  f32x4 acc[2][2][4][2] = {};

  // prologue: A0(0) B0(0) B1(0) A1(0) A0(1) B1(1); keep last 2 halves in flight
  stage_half(pA00, pA01, sm + 0 * 8192 + wbase);
  stage_half(pB00, pB01, sm + 4 * 8192 + wbase);
  stage_half(pB10, pB11, sm + 5 * 8192 + wbase);
  stage_half(pA10, pA11, sm + 1 * 8192 + wbase);
  stage_half(pA00 + 64, pA01 + 64, sm + 2 * 8192 + wbase);
  stage_half(pB10 + 64, pB11 + 64, sm + 7 * 8192 + wbase);
  asm volatile("s_waitcnt vmcnt(4)" ::: "memory");
  __builtin_amdgcn_s_barrier();

  constexpr int NT = HID / 64;   // 32 K-tiles
#pragma unroll 1
  for (int it = 0; it < NT / 2 - 1; ++it) {
    int u = it * 2;
    ktile<0, true, true, 4>(sm, wbase, rA, rB, lquad, pA00, pA01, pA10, pA11,
                            pB00, pB01, pB10, pB11, (u + 1) * 64, (u + 2) * 64, acc);
    ktile<1, true, true, 4>(sm, wbase, rA, rB, lquad, pA00, pA01, pA10, pA11,
                            pB00, pB01, pB10, pB11, (u + 2) * 64, (u + 3) * 64, acc);
  }
  ktile<0, true, false, 0>(sm, wbase, rA, rB, lquad, pA00, pA01, pA10, pA11,
                           pB00, pB01, pB10, pB11, (NT - 1) * 64, 0, acc);
  ktile<1, false, false, -1>(sm, wbase, rA, rB, lquad, pA00, pA01, pA10, pA11,
                             pB00, pB01, pB10, pB11, 0, 0, acc);

  // epilogue: gelu(gate)*up -> act (bh0 = gate, bh1 = up)
  size_t actb = (size_t)row0 * INTER + (size_t)nt * 128 + wng * 32 + lrow;
#pragma unroll
  for (int ah = 0; ah < 2; ++ah)
#pragma unroll
    for (int i = 0; i < 4; ++i)
#pragma unroll
      for (int r = 0; r < 4; ++r) {
        int m = ah * 128 + wmg * 64 + i * 16 + lquad * 4 + r;
#pragma unroll
        for (int j = 0; j < 2; ++j) {
          float g = acc[ah][0][i][j][r], u = acc[ah][1][i][j][r];
          // 0.5*g*(1+tanh(y))*u == g*u*sigmoid(2y), y=0.79788456*(g+0.044715 g^3)
          float z = 1.5957691f * (g + 0.044715f * g * g * g);
          float aout = g * u / (1.f + __expf(-z));
          act[actb + (size_t)m * INTER + j * 16] = f2bf(aout);
        }
      }
}

// ------------------------------------------------- down GEMM + scatter-add ---
__global__ __launch_bounds__(512, 2) void gemm_down8(
    const unsigned short* __restrict__ act,   // [rows][INTER] bf16
    const unsigned short* __restrict__ dwT,   // [E][HID][INTER] bf16
    const int* __restrict__ rows, const float* __restrict__ wgt,
    const int* __restrict__ offs, void* __restrict__ outv,
    const int* __restrict__ flagp) {
  extern __shared__ unsigned short sm[];
  int nRT = offs[NEXP] >> 8;
  int rowTile = blockIdx.x >> 3;
  if (rowTile >= nRT) return;
  int nt = blockIdx.x & 7;                    // 8 n-tiles of 256 out cols
  int row0 = rowTile << 8;
  int e = 0;
  while (row0 >= offs[e + 1]) ++e;

  int tid = threadIdx.x;
  int lane = tid & 63, lrow = lane & 15, lquad = lane >> 4;
  int wave = tid >> 6;
  int wmg = wave >> 2, wng = wave & 3;
  int wbase = wave << 9;
  int rA = wmg * 64 + lrow;
  int rB = wng * 32 + lrow;

  int sr = tid >> 3;
  int swz = ((tid & 7) ^ (sr & 7)) << 3;

  const unsigned short* pA00 = act + (size_t)(row0 + sr) * INTER + swz;
  const unsigned short* pA01 = act + (size_t)(row0 + 64 + sr) * INTER + swz;
  const unsigned short* pA10 = act + (size_t)(row0 + 128 + sr) * INTER + swz;
  const unsigned short* pA11 = act + (size_t)(row0 + 192 + sr) * INTER + swz;
  const unsigned short* dB = dwT + ((size_t)e * HID + (size_t)nt * 256) * INTER;
  const unsigned short* pB00 = dB + (size_t)sr * INTER + swz;
  const unsigned short* pB01 = dB + (size_t)(64 + sr) * INTER + swz;
  const unsigned short* pB10 = dB + (size_t)(128 + sr) * INTER + swz;
  const unsigned short* pB11 = dB + (size_t)(192 + sr) * INTER + swz;

  f32x4 acc[2][2][4][2] = {};

  stage_half(pA00, pA01, sm + 0 * 8192 + wbase);
  stage_half(pB00, pB01, sm + 4 * 8192 + wbase);
  stage_half(pB10, pB11, sm + 5 * 8192 + wbase);
  stage_half(pA10, pA11, sm + 1 * 8192 + wbase);
  stage_half(pA00 + 64, pA01 + 64, sm + 2 * 8192 + wbase);
  stage_half(pB10 + 64, pB11 + 64, sm + 7 * 8192 + wbase);
  asm volatile("s_waitcnt vmcnt(4)" ::: "memory");
  __builtin_amdgcn_s_barrier();

  constexpr int NT = INTER / 64;   // 16 K-tiles
#pragma unroll 1
  for (int it = 0; it < NT / 2 - 1; ++it) {
    int u = it * 2;
    ktile<0, true, true, 4>(sm, wbase, rA, rB, lquad, pA00, pA01, pA10, pA11,
                            pB00, pB01, pB10, pB11, (u + 1) * 64, (u + 2) * 64, acc);
    ktile<1, true, true, 4>(sm, wbase, rA, rB, lquad, pA00, pA01, pA10, pA11,
                            pB00, pB01, pB10, pB11, (u + 2) * 64, (u + 3) * 64, acc);
  }
  ktile<0, true, false, 0>(sm, wbase, rA, rB, lquad, pA00, pA01, pA10, pA11,
                           pB00, pB01, pB10, pB11, (NT - 1) * 64, 0, acc);
  ktile<1, false, false, -1>(sm, wbase, rA, rB, lquad, pA00, pA01, pA10, pA11,
                             pB00, pB01, pB10, pB11, 0, 0, acc);

  int flag = *flagp;
#pragma unroll
  for (int ah = 0; ah < 2; ++ah)
#pragma unroll
    for (int i = 0; i < 4; ++i)
#pragma unroll
      for (int r = 0; r < 4; ++r) {
        int m = row0 + ah * 128 + wmg * 64 + i * 16 + lquad * 4 + r;
        float w = wgt[m];
        int token = rows[m];
        size_t base = (size_t)token * HID + (size_t)nt * 256 + wng * 32 + lrow;
        if (flag) {
          // bf16 output: pack (even,odd) column pair, CAS accumulate
#pragma unroll
          for (int bh = 0; bh < 2; ++bh)
#pragma unroll
            for (int j = 0; j < 2; ++j) {
              float v = acc[ah][bh][i][j][r] * w;
              float o = __shfl_xor(v, 1);   // partner column (col^1)
              if (((lane & 1) == 0) && w != 0.f) {
                unsigned* p = (unsigned*)((unsigned short*)outv + base + bh * 128 + j * 16);
                unsigned old = __atomic_load_n(p, __ATOMIC_RELAXED), assumed;
                do {
                  assumed = old;
                  float flo = bf2f((unsigned short)(assumed & 0xffffu));
                  float fhi = bf2f((unsigned short)(assumed >> 16));
                  unsigned nw = (unsigned)f2bf(flo + v) | ((unsigned)f2bf(fhi + o) << 16);
                  old = atomicCAS(p, assumed, nw);
                } while (old != assumed);
              }
            }
        } else {
          if (w != 0.f) {
            float* outf = (float*)outv;
#pragma unroll
            for (int bh = 0; bh < 2; ++bh)
#pragma unroll
              for (int j = 0; j < 2; ++j)
                atomicAdd(outf + base + bh * 128 + j * 16, acc[ah][bh][i][j][r] * w);
          }
        }
      }
}

// ------------------------------------------------------------------ launch ---
extern "C" void kernel_launch(void* const* d_in, const int* in_sizes, int n_in,
                              void* d_out, int out_size, void* d_ws, size_t ws_size,
                              hipStream_t stream) {
  (void)in_sizes; (void)n_in; (void)out_size; (void)ws_size;
  const void* x   = d_in[0];
  const int* sel  = (const int*)d_in[1];
  const void* rw  = d_in[2];
  const void* gw  = d_in[3];
  const void* uw  = d_in[4];
  const void* dw  = d_in[5];

  char* ws = (char*)d_ws;
  int* offs  = (int*)ws;                     // ints 0..8
  int* flagp = (int*)(ws + 64);              // dtype flag
  int* rows  = (int*)(ws + 256);             // 18432 ints
  float* wgt = (float*)(ws + 256 + MAX_ROWS * 4);
  unsigned short* gwT = (unsigned short*)(ws + 256 + MAX_ROWS * 8);
  unsigned short* uwT = gwT + (size_t)NEXP * HID * INTER;
  unsigned short* dwT = uwT + (size_t)NEXP * HID * INTER;
  unsigned short* xc  = dwT + (size_t)NEXP * HID * INTER;  // [T][HID] bf16
  unsigned short* act = xc + (size_t)T_TOK * HID;          // [18432][1024] bf16

  // 128 KiB dynamic LDS opt-in (unconditional; host-side, graph-capture-safe)
  hipFuncSetAttribute(reinterpret_cast<const void*>(gemm_gateup8),
                      hipFuncAttributeMaxDynamicSharedMemorySize, 131072);
  hipFuncSetAttribute(reinterpret_cast<const void*>(gemm_down8),
                      hipFuncAttributeMaxDynamicSharedMemorySize, 131072);

  detect_k<<<1, 64, 0, stream>>>((const unsigned*)x, flagp);
  zero_out_k<<<4096, 256, 0, stream>>>((unsigned*)d_out, flagp);
  routing_k<<<1, 256, 0, stream>>>(sel, rw, rows, wgt, offs, flagp);
  transpose_k<<<dim3(INTER / 64, HID / 64, NEXP), 256, 0, stream>>>(gw, gwT, HID, INTER, flagp);
  transpose_k<<<dim3(INTER / 64, HID / 64, NEXP), 256, 0, stream>>>(uw, uwT, HID, INTER, flagp);
  transpose_k<<<dim3(HID / 64, INTER / 64, NEXP), 256, 0, stream>>>(dw, dwT, INTER, HID, flagp);
  convert_x_k<<<4096, 256, 0, stream>>>(x, xc, flagp);
  gemm_gateup8<<<MAX_RT * 8, 512, 131072, stream>>>(xc, gwT, uwT, rows, offs, act);
  gemm_down8<<<MAX_RT * 8, 512, 131072, stream>>>(act, dwT, rows, wgt, offs, d_out, flagp);
}

// Round 9
// 583.095 us; speedup vs baseline: 1.2632x; 1.1859x over previous
//
#include <hip/hip_runtime.h>
#include <hip/hip_bf16.h>

// MoE (Gemma 8-expert top-2) sparse bf16 MFMA implementation.
// R6 (resubmit after infra timeout): fixes R5's transpose output bug
// (uint4 = 8 shorts, but ch stride was 16 shorts -> half of every transposed
// weight row never written; absmax 2.9). Each thread now stores two
// consecutive uint4 (full 16-short span). Everything else byte-identical:
//   - GEMM inner loops: 8-phase template (measured 691us e2e in R4, conflict 0)
//   - down epilogue: y-buffer fp32 partials + combine kernel (no atomics);
//     ws-size gated with R4's atomic path as fallback
//   - routing_k at 1024 threads, emits pairpos[] inverse map

typedef __attribute__((ext_vector_type(8))) short bf16x8;
typedef __attribute__((ext_vector_type(4))) float f32x4;
typedef __attribute__((ext_vector_type(4))) unsigned short us4;

#define AS1 __attribute__((address_space(1)))
#define AS3 __attribute__((address_space(3)))

static constexpr int T_TOK = 8192;
static constexpr int HID   = 2048;
static constexpr int INTER = 1024;
static constexpr int NEXP  = 8;
static constexpr int NPAIR = T_TOK * 2;            // 16384 (token, slot) pairs
static constexpr int TM    = 256;                  // row tile (pairs), 8-phase BM
static constexpr int MAX_ROWS = NPAIR + NEXP * TM; // 18432 padded rows max
static constexpr int MAX_RT   = MAX_ROWS / TM;     // 72 row tiles max
static constexpr int OUTN = T_TOK * HID;           // 16,777,216 out elements

__device__ __forceinline__ unsigned short f2bf(float f) {
  unsigned u = __float_as_uint(f);
  u += 0x7fffu + ((u >> 16) & 1u);   // RNE
  return (unsigned short)(u >> 16);
}
__device__ __forceinline__ float bf2f(unsigned short h) {
  return __uint_as_float(((unsigned)h) << 16);
}
__device__ __forceinline__ void glds16(const void* g, void* l) {
  __builtin_amdgcn_global_load_lds((const AS1 void*)g, (AS3 void*)l, 16, 0, 0);
}

// ----------------------------------------------------------- dtype detect ---
__global__ void detect_k(const unsigned* __restrict__ xw, int* __restrict__ flagp) {
  int tid = threadIdx.x;   // 64 threads
  int cnt = 0;
  for (int i = tid; i < 256; i += 64) {
    unsigned e = (xw[i] >> 7) & 0xffu;   // exponent of low-half bf16
    cnt += (e >= 0x70u && e <= 0x8fu) ? 1 : 0;
  }
  for (int off = 32; off; off >>= 1) cnt += __shfl_down(cnt, off);
  if (tid == 0) *flagp = (cnt >= 192) ? 1 : 0;
}

// -------------------------------------------------------------- zero out ----
// Only launched on the atomic-fallback path.
__global__ void zero_out_k(unsigned* __restrict__ out, const int* __restrict__ flagp) {
  int n = (*flagp) ? (OUTN / 2) : OUTN;   // u32 words
  int i = blockIdx.x * 256 + threadIdx.x;
  int stride = gridDim.x * 256;
  for (; i < n; i += stride) out[i] = 0u;
}

// ---------------------------------------------------------------- routing ---
__global__ void routing_k(const int* __restrict__ sel, const void* __restrict__ rwv,
                          int* __restrict__ rows, float* __restrict__ wgt,
                          int* __restrict__ offs, int* __restrict__ pairpos,
                          const int* __restrict__ flagp) {
  __shared__ int cnt[NEXP], cur[NEXP], offs_s[NEXP + 1];
  int flag = *flagp;
  const unsigned short* rw16 = (const unsigned short*)rwv;
  const float* rwf = (const float*)rwv;
  int tid = threadIdx.x;   // 1024 threads
  if (tid < NEXP) cnt[tid] = 0;
  __syncthreads();
  for (int p = tid; p < NPAIR; p += 1024) atomicAdd(&cnt[sel[p]], 1);
  __syncthreads();
  if (tid == 0) {
    int off = 0;
    for (int e = 0; e < NEXP; ++e) {
      offs_s[e] = off; cur[e] = off;
      off += (cnt[e] + TM - 1) / TM * TM;   // pad each expert to TM rows
    }
    offs_s[NEXP] = off;
  }
  __syncthreads();
  if (tid <= NEXP) offs[tid] = offs_s[tid];
  for (int p = tid; p < NPAIR; p += 1024) {
    int e = sel[p];
    int pos = atomicAdd(&cur[e], 1);
    rows[pos] = p >> 1;                                 // token index
    wgt[pos] = flag ? bf2f(rw16[p]) : rwf[p];           // routing weight
    pairpos[p] = pos;                                   // inverse map for combine
  }
  for (int e = 0; e < NEXP; ++e)
    for (int r = offs_s[e] + cnt[e] + tid; r < offs_s[e + 1]; r += 1024) {
      rows[r] = 0; wgt[r] = 0.f;   // padding rows: token 0, weight 0
    }
}

// --------------------------------------------------------- x canonicalize ---
__global__ void convert_x_k(const void* __restrict__ xin,
                            unsigned short* __restrict__ xc,
                            const int* __restrict__ flagp) {
  int flag = *flagp;
  const int nvec = (T_TOK * HID) / 8;   // 8 elements per iter
  int v = blockIdx.x * 256 + threadIdx.x;
  int stride = gridDim.x * 256;
  for (; v < nvec; v += stride) {
    if (flag) {
      ((uint4*)xc)[v] = ((const uint4*)xin)[v];
    } else {
      const float4* s = (const float4*)xin;
      float4 a = s[2 * v], b = s[2 * v + 1];
      uint4 o;
      o.x = (unsigned)f2bf(a.x) | ((unsigned)f2bf(a.y) << 16);
      o.y = (unsigned)f2bf(a.z) | ((unsigned)f2bf(a.w) << 16);
      o.z = (unsigned)f2bf(b.x) | ((unsigned)f2bf(b.y) << 16);
      o.w = (unsigned)f2bf(b.z) | ((unsigned)f2bf(b.w) << 16);
      ((uint4*)xc)[v] = o;
    }
  }
}

// -------------------------------------------------------------- transpose ---
// in: [E][R][C] (fp32 or bf16) -> out: [E][C][R] bf16, 64x64 tiles.
// 4x4 micro-tile per thread into a stride-72 LDS tile (transposed position);
// output: 4 threads per row x TWO uint4 each = full 64-short row (R6 fix).
__global__ void transpose_k(const void* __restrict__ in,
                            unsigned short* __restrict__ out, int R, int C,
                            const int* __restrict__ flagp) {
  __shared__ unsigned short t[64 * 72];   // row stride 72 shorts (144B, 16B-aligned)
  int flag = *flagp;
  int e = blockIdx.z;
  int c0 = blockIdx.x * 64, r0 = blockIdx.y * 64;
  int tid = threadIdx.x;                  // 256 threads
  int mr = tid >> 4;                      // 0..15: rows  mr*4..mr*4+3
  int mc = tid & 15;                      // 0..15: cols  mc*4..mc*4+3
  unsigned short b[4][4];                 // [i][j] = bf16(in[r0+mr*4+i][c0+mc*4+j])
  if (flag) {
    const unsigned short* src = (const unsigned short*)in + (size_t)e * R * C;
#pragma unroll
    for (int i = 0; i < 4; ++i) {
      us4 v = *(const us4*)(src + (size_t)(r0 + mr * 4 + i) * C + c0 + mc * 4);
      b[i][0] = v[0]; b[i][1] = v[1]; b[i][2] = v[2]; b[i][3] = v[3];
    }
  } else {
    const float* src = (const float*)in + (size_t)e * R * C;
#pragma unroll
    for (int i = 0; i < 4; ++i) {
      float4 v = *(const float4*)(src + (size_t)(r0 + mr * 4 + i) * C + c0 + mc * 4);
      b[i][0] = f2bf(v.x); b[i][1] = f2bf(v.y); b[i][2] = f2bf(v.z); b[i][3] = f2bf(v.w);
    }
  }
#pragma unroll
  for (int j = 0; j < 4; ++j) {
    us4 w;
    w[0] = b[0][j]; w[1] = b[1][j]; w[2] = b[2][j]; w[3] = b[3][j];
    *(us4*)(&t[(mc * 4 + j) * 72 + mr * 4]) = w;   // transposed position
  }
  __syncthreads();
  // 4 threads per output row; each stores 16 shorts (2x uint4) -> full row.
  int orow = tid >> 2, ch = (tid & 3) * 16;
  uint4 v0 = *(const uint4*)(&t[orow * 72 + ch]);
  uint4 v1 = *(const uint4*)(&t[orow * 72 + ch + 8]);
  unsigned short* dst = out + (size_t)e * R * C + (size_t)(c0 + orow) * R + r0 + ch;
  *(uint4*)(dst) = v0;
  *(uint4*)(dst + 8) = v1;
}

// ===================== 8-phase 256-row GEMM template ========================
// (unchanged from R4 — verified: bank-conflict 0, passed harness)

__device__ __forceinline__ const bf16x8* ldf(const unsigned short* sm, int slot,
                                             int r, int c8) {
  return (const bf16x8*)(sm + slot * 8192 + r * 64 + ((c8 ^ (r & 7)) << 3));
}
__device__ __forceinline__ void stage_half(const unsigned short* p0,
                                           const unsigned short* p1,
                                           unsigned short* dst) {
  glds16(p0, dst);
  glds16(p1, dst + 4096);
}

#define MFMA8(AH, BH, B)                                                       \
  _Pragma("unroll") for (int i_ = 0; i_ < 4; ++i_) {                           \
    _Pragma("unroll") for (int j_ = 0; j_ < 2; ++j_) {                         \
      acc[AH][BH][i_][j_] = __builtin_amdgcn_mfma_f32_16x16x32_bf16(           \
          a[i_][0], B[j_][0], acc[AH][BH][i_][j_], 0, 0, 0);                   \
      acc[AH][BH][i_][j_] = __builtin_amdgcn_mfma_f32_16x16x32_bf16(           \
          a[i_][1], B[j_][1], acc[AH][BH][i_][j_], 0, 0, 0);                   \
    }                                                                          \
  }

template <int BUF, bool S1, bool S2, int VM>
__device__ __forceinline__ void ktile(
    unsigned short* sm, int wbase, int rA, int rB, int lquad,
    const unsigned short* pA00, const unsigned short* pA01,
    const unsigned short* pA10, const unsigned short* pA11,
    const unsigned short* pB00, const unsigned short* pB01,
    const unsigned short* pB10, const unsigned short* pB11,
    int ko1, int ko2, f32x4 (&acc)[2][2][4][2]) {
  bf16x8 a[4][2], b0[2][2], b1[2][2];
  // -------- phase 1: A0 x B0 ; stage A1(u+1) -> buf^1
#pragma unroll
  for (int i = 0; i < 4; ++i)
#pragma unroll
    for (int k = 0; k < 2; ++k)
      a[i][k] = *ldf(sm, BUF * 2 + 0, rA + i * 16, k * 4 + lquad);
#pragma unroll
  for (int j = 0; j < 2; ++j)
#pragma unroll
    for (int k = 0; k < 2; ++k)
      b0[j][k] = *ldf(sm, 4 + BUF * 2 + 0, rB + j * 16, k * 4 + lquad);
  if constexpr (S1)
    stage_half(pA10 + ko1, pA11 + ko1, sm + ((BUF ^ 1) * 2 + 1) * 8192 + wbase);
  __builtin_amdgcn_s_barrier();
  asm volatile("s_waitcnt lgkmcnt(0)" ::: "memory");
  __builtin_amdgcn_s_setprio(1);
  MFMA8(0, 0, b0);
  __builtin_amdgcn_s_setprio(0);
  __builtin_amdgcn_s_barrier();
  // -------- phase 2: A0 x B1 ; stage B0(u+1) -> buf^1
#pragma unroll
  for (int j = 0; j < 2; ++j)
#pragma unroll
    for (int k = 0; k < 2; ++k)
      b1[j][k] = *ldf(sm, 4 + BUF * 2 + 1, rB + j * 16, k * 4 + lquad);
  if constexpr (S1)
    stage_half(pB00 + ko1, pB01 + ko1, sm + (4 + (BUF ^ 1) * 2 + 0) * 8192 + wbase);
  __builtin_amdgcn_s_barrier();
  asm volatile("s_waitcnt lgkmcnt(0)" ::: "memory");
  __builtin_amdgcn_s_setprio(1);
  MFMA8(0, 1, b1);
  __builtin_amdgcn_s_setprio(0);
  __builtin_amdgcn_s_barrier();
  // -------- phase 3: A1 x B1 ; stage A0(u+2) -> buf
#pragma unroll
  for (int i = 0; i < 4; ++i)
#pragma unroll
    for (int k = 0; k < 2; ++k)
      a[i][k] = *ldf(sm, BUF * 2 + 1, rA + i * 16, k * 4 + lquad);
  if constexpr (S2)
    stage_half(pA00 + ko2, pA01 + ko2, sm + (BUF * 2 + 0) * 8192 + wbase);
  __builtin_amdgcn_s_barrier();
  asm volatile("s_waitcnt lgkmcnt(0)" ::: "memory");
  __builtin_amdgcn_s_setprio(1);
  MFMA8(1, 1, b1);
  __builtin_amdgcn_s_setprio(0);
  __builtin_amdgcn_s_barrier();
  // -------- phase 4: A1 x B0 ; stage B1(u+2) -> buf ; counted vmcnt
  if constexpr (S2)
    stage_half(pB10 + ko2, pB11 + ko2, sm + (4 + BUF * 2 + 1) * 8192 + wbase);
  __builtin_amdgcn_s_barrier();
  __builtin_amdgcn_s_setprio(1);
  MFMA8(1, 0, b0);
  __builtin_amdgcn_s_setprio(0);
  if constexpr (VM == 4)
    asm volatile("s_waitcnt vmcnt(4)" ::: "memory");
  else if constexpr (VM == 0)
    asm volatile("s_waitcnt vmcnt(0)" ::: "memory");
  __builtin_amdgcn_s_barrier();
}

// ------------------------------------------------------ gate/up fused GEMM ---
__global__ __launch_bounds__(512, 2) void gemm_gateup8(
    const unsigned short* __restrict__ xc,    // [T][HID] bf16
    const unsigned short* __restrict__ gwT,   // [E][INTER][HID] bf16
    const unsigned short* __restrict__ uwT,   // [E][INTER][HID] bf16
    const int* __restrict__ rows, const int* __restrict__ offs,
    unsigned short* __restrict__ act) {
  extern __shared__ unsigned short sm[];
  int nRT = offs[NEXP] >> 8;
  int rowTile = blockIdx.x >> 3;
  if (rowTile >= nRT) return;
  int nt = blockIdx.x & 7;                    // 8 n-tiles of 128 act cols
  int row0 = rowTile << 8;
  int e = 0;
  while (row0 >= offs[e + 1]) ++e;

  int tid = threadIdx.x;
  int lane = tid & 63, lrow = lane & 15, lquad = lane >> 4;
  int wave = tid >> 6;
  int wmg = wave >> 2, wng = wave & 3;
  int wbase = wave << 9;                      // *512 shorts
  int rA = wmg * 64 + lrow;
  int rB = wng * 32 + lrow;

  int sr = tid >> 3;                          // 0..63 row in staging round
  int swz = ((tid & 7) ^ (sr & 7)) << 3;      // pre-swizzled source chunk

  const unsigned short* pA00 = xc + (size_t)rows[row0 + sr] * HID + swz;
  const unsigned short* pA01 = xc + (size_t)rows[row0 + 64 + sr] * HID + swz;
  const unsigned short* pA10 = xc + (size_t)rows[row0 + 128 + sr] * HID + swz;
  const unsigned short* pA11 = xc + (size_t)rows[row0 + 192 + sr] * HID + swz;
  const unsigned short* gB = gwT + ((size_t)e * INTER + (size_t)nt * 128) * HID;
  const unsigned short* uB = uwT + ((size_t)e * INTER + (size_t)nt * 128) * HID;
  const unsigned short* pB00 = gB + (size_t)sr * HID + swz;
  const unsigned short* pB01 = gB + (size_t)(64 + sr) * HID + swz;
  const unsigned short* pB10 = uB + (size_t)sr * HID + swz;
  const unsigned short* pB11 = uB + (size_t)(64 + sr) * HID + swz;

  f32x4 acc[2][2][4][2] = {};

  stage_half(pA00, pA01, sm + 0 * 8192 + wbase);
  stage_half(pB00, pB01, sm + 4 * 8192 + wbase);
  stage_half(pB10, pB11, sm + 5 * 8192 + wbase);
  stage_half(pA10, pA11, sm + 1 * 8192 + wbase);
  stage_half(pA00 + 64, pA01 + 64, sm + 2 * 8192 + wbase);
  stage_half(pB10 + 64, pB11 + 64, sm + 7 * 8192 + wbase);
  asm volatile("s_waitcnt vmcnt(4)" ::: "memory");
  __builtin_amdgcn_s_barrier();

  constexpr int NT = HID / 64;   // 32 K-tiles
#pragma unroll 1
  for (int it = 0; it < NT / 2 - 1; ++it) {
    int u = it * 2;
    ktile<0, true, true, 4>(sm, wbase, rA, rB, lquad, pA00, pA01, pA10, pA11,
                            pB00, pB01, pB10, pB11, (u + 1) * 64, (u + 2) * 64, acc);
    ktile<1, true, true, 4>(sm, wbase, rA, rB, lquad, pA00, pA01, pA10, pA11,
                            pB00, pB01, pB10, pB11, (u + 2) * 64, (u + 3) * 64, acc);
  }
  ktile<0, true, false, 0>(sm, wbase, rA, rB, lquad, pA00, pA01, pA10, pA11,
                           pB00, pB01, pB10, pB11, (NT - 1) * 64, 0, acc);
  ktile<1, false, false, -1>(sm, wbase, rA, rB, lquad, pA00, pA01, pA10, pA11,
                             pB00, pB01, pB10, pB11, 0, 0, acc);

  // epilogue: gelu(gate)*up -> act (bh0 = gate, bh1 = up)
  size_t actb = (size_t)row0 * INTER + (size_t)nt * 128 + wng * 32 + lrow;
#pragma unroll
  for (int ah = 0; ah < 2; ++ah)
#pragma unroll
    for (int i = 0; i < 4; ++i)
#pragma unroll
      for (int r = 0; r < 4; ++r) {
        int m = ah * 128 + wmg * 64 + i * 16 + lquad * 4 + r;
#pragma unroll
        for (int j = 0; j < 2; ++j) {
          float g = acc[ah][0][i][j][r], u = acc[ah][1][i][j][r];
          float z = 1.5957691f * (g + 0.044715f * g * g * g);
          float aout = g * u / (1.f + __expf(-z));
          act[actb + (size_t)m * INTER + j * 16] = f2bf(aout);
        }
      }
}

// ------------------------------------------------- down GEMM + epilogue -----
// EPI=1: weighted partials -> y[m][HID] (plain stores, combine later)
// EPI=0: atomic scatter-add into out (fallback when ws too small for y)
template <int EPI>
__global__ __launch_bounds__(512, 2) void gemm_down8(
    const unsigned short* __restrict__ act,   // [rows][INTER] bf16
    const unsigned short* __restrict__ dwT,   // [E][HID][INTER] bf16
    const int* __restrict__ rows, const float* __restrict__ wgt,
    const int* __restrict__ offs, void* __restrict__ outv,
    const int* __restrict__ flagp, float* __restrict__ y) {
  extern __shared__ unsigned short sm[];
  int nRT = offs[NEXP] >> 8;
  int rowTile = blockIdx.x >> 3;
  if (rowTile >= nRT) return;
  int nt = blockIdx.x & 7;                    // 8 n-tiles of 256 out cols
  int row0 = rowTile << 8;
  int e = 0;
  while (row0 >= offs[e + 1]) ++e;

  int tid = threadIdx.x;
  int lane = tid & 63, lrow = lane & 15, lquad = lane >> 4;
  int wave = tid >> 6;
  int wmg = wave >> 2, wng = wave & 3;
  int wbase = wave << 9;
  int rA = wmg * 64 + lrow;
  int rB = wng * 32 + lrow;

  int sr = tid >> 3;
  int swz = ((tid & 7) ^ (sr & 7)) << 3;

  const unsigned short* pA00 = act + (size_t)(row0 + sr) * INTER + swz;
  const unsigned short* pA01 = act + (size_t)(row0 + 64 + sr) * INTER + swz;
  const unsigned short* pA10 = act + (size_t)(row0 + 128 + sr) * INTER + swz;
  const unsigned short* pA11 = act + (size_t)(row0 + 192 + sr) * INTER + swz;
  const unsigned short* dB = dwT + ((size_t)e * HID + (size_t)nt * 256) * INTER;
  const unsigned short* pB00 = dB + (size_t)sr * INTER + swz;
  const unsigned short* pB01 = dB + (size_t)(64 + sr) * INTER + swz;
  const unsigned short* pB10 = dB + (size_t)(128 + sr) * INTER + swz;
  const unsigned short* pB11 = dB + (size_t)(192 + sr) * INTER + swz;

  f32x4 acc[2][2][4][2] = {};

  stage_half(pA00, pA01, sm + 0 * 8192 + wbase);
  stage_half(pB00, pB01, sm + 4 * 8192 + wbase);
  stage_half(pB10, pB11, sm + 5 * 8192 + wbase);
  stage_half(pA10, pA11, sm + 1 * 8192 + wbase);
  stage_half(pA00 + 64, pA01 + 64, sm + 2 * 8192 + wbase);
  stage_half(pB10 + 64, pB11 + 64, sm + 7 * 8192 + wbase);
  asm volatile("s_waitcnt vmcnt(4)" ::: "memory");
  __builtin_amdgcn_s_barrier();

  constexpr int NT = INTER / 64;   // 16 K-tiles
#pragma unroll 1
  for (int it = 0; it < NT / 2 - 1; ++it) {
    int u = it * 2;
    ktile<0, true, true, 4>(sm, wbase, rA, rB, lquad, pA00, pA01, pA10, pA11,
                            pB00, pB01, pB10, pB11, (u + 1) * 64, (u + 2) * 64, acc);
    ktile<1, true, true, 4>(sm, wbase, rA, rB, lquad, pA00, pA01, pA10, pA11,
                            pB00, pB01, pB10, pB11, (u + 2) * 64, (u + 3) * 64, acc);
  }
  ktile<0, true, false, 0>(sm, wbase, rA, rB, lquad, pA00, pA01, pA10, pA11,
                           pB00, pB01, pB10, pB11, (NT - 1) * 64, 0, acc);
  ktile<1, false, false, -1>(sm, wbase, rA, rB, lquad, pA00, pA01, pA10, pA11,
                             pB00, pB01, pB10, pB11, 0, 0, acc);

  if constexpr (EPI == 1) {
    // plain stores of weighted partials; combine kernel sums the two pairs
#pragma unroll
    for (int ah = 0; ah < 2; ++ah)
#pragma unroll
      for (int i = 0; i < 4; ++i)
#pragma unroll
        for (int r = 0; r < 4; ++r) {
          int m = row0 + ah * 128 + wmg * 64 + i * 16 + lquad * 4 + r;
          float w = wgt[m];
          float* yp = y + (size_t)m * HID + (size_t)nt * 256 + wng * 32 + lrow;
#pragma unroll
          for (int bh = 0; bh < 2; ++bh)
#pragma unroll
            for (int j = 0; j < 2; ++j)
              yp[bh * 128 + j * 16] = acc[ah][bh][i][j][r] * w;
        }
  } else {
    int flag = *flagp;
#pragma unroll
    for (int ah = 0; ah < 2; ++ah)
#pragma unroll
      for (int i = 0; i < 4; ++i)
#pragma unroll
        for (int r = 0; r < 4; ++r) {
          int m = row0 + ah * 128 + wmg * 64 + i * 16 + lquad * 4 + r;
          float w = wgt[m];
          int token = rows[m];
          size_t base = (size_t)token * HID + (size_t)nt * 256 + wng * 32 + lrow;
          if (flag) {
#pragma unroll
            for (int bh = 0; bh < 2; ++bh)
#pragma unroll
              for (int j = 0; j < 2; ++j) {
                float v = acc[ah][bh][i][j][r] * w;
                float o = __shfl_xor(v, 1);   // partner column (col^1)
                if (((lane & 1) == 0) && w != 0.f) {
                  unsigned* p = (unsigned*)((unsigned short*)outv + base + bh * 128 + j * 16);
                  unsigned old = __atomic_load_n(p, __ATOMIC_RELAXED), assumed;
                  do {
                    assumed = old;
                    float flo = bf2f((unsigned short)(assumed & 0xffffu));
                    float fhi = bf2f((unsigned short)(assumed >> 16));
                    unsigned nw = (unsigned)f2bf(flo + v) | ((unsigned)f2bf(fhi + o) << 16);
                    old = atomicCAS(p, assumed, nw);
                  } while (old != assumed);
                }
              }
          } else {
            if (w != 0.f) {
              float* outf = (float*)outv;
#pragma unroll
              for (int bh = 0; bh < 2; ++bh)
#pragma unroll
                for (int j = 0; j < 2; ++j)
                  atomicAdd(outf + base + bh * 128 + j * 16, acc[ah][bh][i][j][r] * w);
            }
          }
        }
  }
}

// ----------------------------------------------------------------- combine ---
// out[t][h] = y[pairpos[2t]][h] + y[pairpos[2t+1]][h]   (fully overwrites out)
__global__ void combine_k(const float* __restrict__ y,
                          const int* __restrict__ pairpos,
                          void* __restrict__ outv, const int* __restrict__ flagp) {
  int flag = *flagp;
  const int NV = T_TOK * (HID / 4);   // float4 groups
  int v = blockIdx.x * 256 + threadIdx.x;
  int stride = gridDim.x * 256;
  for (; v < NV; v += stride) {
    int t = v >> 9;                   // HID/4 = 512 groups per token
    int hq = (v & 511) * 4;
    int p0 = pairpos[2 * t], p1 = pairpos[2 * t + 1];
    float4 a = *(const float4*)(y + (size_t)p0 * HID + hq);
    float4 b = *(const float4*)(y + (size_t)p1 * HID + hq);
    float4 s;
    s.x = a.x + b.x; s.y = a.y + b.y; s.z = a.z + b.z; s.w = a.w + b.w;
    if (flag) {
      uint2 o;
      o.x = (unsigned)f2bf(s.x) | ((unsigned)f2bf(s.y) << 16);
      o.y = (unsigned)f2bf(s.z) | ((unsigned)f2bf(s.w) << 16);
      *(uint2*)((unsigned short*)outv + (size_t)v * 4) = o;
    } else {
      *(float4*)((float*)outv + (size_t)v * 4) = s;
    }
  }
}

// ------------------------------------------------------------------ launch ---
extern "C" void kernel_launch(void* const* d_in, const int* in_sizes, int n_in,
                              void* d_out, int out_size, void* d_ws, size_t ws_size,
                              hipStream_t stream) {
  (void)in_sizes; (void)n_in; (void)out_size;
  const void* x   = d_in[0];
  const int* sel  = (const int*)d_in[1];
  const void* rw  = d_in[2];
  const void* gw  = d_in[3];
  const void* uw  = d_in[4];
  const void* dw  = d_in[5];

  // ws layout (y overlaps gwT+uwT+xc, which are dead when gemm_down runs):
  //   [hdr 256B][rows][wgt][pairpos][dwT][act][gwT][uwT][xc][y-extension]
  char* ws = (char*)d_ws;
  int* offs     = (int*)ws;                          // ints 0..8
  int* flagp    = (int*)(ws + 64);                   // dtype flag
  int* rows     = (int*)(ws + 256);                  // 18432 ints
  float* wgt    = (float*)(ws + 256 + MAX_ROWS * 4);
  int* pairpos  = (int*)(ws + 256 + MAX_ROWS * 8);   // 16384 ints
  size_t off0   = 256 + (size_t)MAX_ROWS * 8 + (size_t)NPAIR * 4;  // 213,248
  off0 = (off0 + 255) & ~(size_t)255;
  unsigned short* dwT = (unsigned short*)(ws + off0);
  unsigned short* act = dwT + (size_t)NEXP * HID * INTER;          // 18432x1024 bf16
  // act size = MAX_ROWS * INTER shorts
  unsigned short* gwT = act + (size_t)MAX_ROWS * INTER;
  unsigned short* uwT = gwT + (size_t)NEXP * HID * INTER;
  unsigned short* xc  = uwT + (size_t)NEXP * HID * INTER;          // [T][HID] bf16
  float* y            = (float*)gwT;                               // overlaps gwT..xc
  size_t y_end = ((char*)gwT - ws) + (size_t)MAX_ROWS * HID * 4;   // ~212.4 MB
  bool use_y = ws_size >= y_end;

  hipFuncSetAttribute(reinterpret_cast<const void*>(gemm_gateup8),
                      hipFuncAttributeMaxDynamicSharedMemorySize, 131072);
  hipFuncSetAttribute(reinterpret_cast<const void*>(gemm_down8<1>),
                      hipFuncAttributeMaxDynamicSharedMemorySize, 131072);
  hipFuncSetAttribute(reinterpret_cast<const void*>(gemm_down8<0>),
                      hipFuncAttributeMaxDynamicSharedMemorySize, 131072);

  detect_k<<<1, 64, 0, stream>>>((const unsigned*)x, flagp);
  if (!use_y)
    zero_out_k<<<4096, 256, 0, stream>>>((unsigned*)d_out, flagp);
  routing_k<<<1, 1024, 0, stream>>>(sel, rw, rows, wgt, offs, pairpos, flagp);
  transpose_k<<<dim3(INTER / 64, HID / 64, NEXP), 256, 0, stream>>>(gw, gwT, HID, INTER, flagp);
  transpose_k<<<dim3(INTER / 64, HID / 64, NEXP), 256, 0, stream>>>(uw, uwT, HID, INTER, flagp);
  transpose_k<<<dim3(HID / 64, INTER / 64, NEXP), 256, 0, stream>>>(dw, dwT, INTER, HID, flagp);
  convert_x_k<<<4096, 256, 0, stream>>>(x, xc, flagp);
  gemm_gateup8<<<MAX_RT * 8, 512, 131072, stream>>>(xc, gwT, uwT, rows, offs, act);
  if (use_y) {
    gemm_down8<1><<<MAX_RT * 8, 512, 131072, stream>>>(act, dwT, rows, wgt, offs,
                                                       d_out, flagp, y);
    combine_k<<<4096, 256, 0, stream>>>(y, pairpos, d_out, flagp);
  } else {
    gemm_down8<0><<<MAX_RT * 8, 512, 131072, stream>>>(act, dwT, rows, wgt, offs,
                                                       d_out, flagp, nullptr);
  }
}